// Round 2
// baseline (328.651 us; speedup 1.0000x reference)
//
#include <hip/hip_runtime.h>

// Native 4-wide float vector (lowers to global_load/store_dwordx4).
typedef float f4 __attribute__((ext_vector_type(4)));

// Problem constants (from reference)
constexpr int OUTP = 32;        // OUT_PLANES
constexpr int INP  = 16;        // IN_PLANES
constexpr int REPS = 16;        // REP = 256/16
constexpr int BB   = 8;
constexpr int HW   = 32 * 32;   // 1024 pixels
constexpr int P4   = HW / 4;    // 256 f4 per channel
constexpr size_t OUT1_F4 = (size_t)BB * OUTP * INP * REPS * P4;  // 16777216 f4

// MEASUREMENT ROUND: this kernel is identical to round 1. kernel_launch
// enqueues it TWICE (idempotent: deterministic, reads only inputs, writes
// the full output). The harness's fixed poison-fill overhead F cancels in
// dur(round2) - dur(round1) = T_kernel, disambiguating:
//   A) T_kernel ~ 106us (headroom vs 42.6us write floor -> keep optimizing)
//   B) T_kernel ~  60us (near floor; visible gap is hidden harness fills)
__global__ __launch_bounds__(256, 4) void qconv_pw_fused(
    const f4* __restrict__ x,      // (B, 256, H, W) as f4: (b*256+c)*P4 + v
    const f4* __restrict__ x2,     // (B, 16, H, W)
    const float* __restrict__ w,   // (512,) == w2[o][i] at w[o*16+i]
    f4* __restrict__ out)          // out1 (B,8192,H,W) then relu_out2 (B,32,H,W)
{
    const int blk = blockIdx.x;
    const int tid = threadIdx.x;

    if (blk < 256) {
        // ---- relu_out2 path (first, so it never tails) ----
        const int t    = blk * 256 + tid;          // [0, 65536)
        const int v    = t & (P4 - 1);             // f4 pixel index
        const int rest = t >> 8;                   // [0, 256) = B*OUTP
        const int o    = rest & (OUTP - 1);
        const int b    = rest >> 5;

        const f4* xb = x2 + (size_t)(b * INP) * P4 + v;
        f4 acc = (f4)(0.f);
#pragma unroll
        for (int i = 0; i < INP; ++i) {
            const float wo = w[o * INP + i];       // wave-uniform -> scalar load
            acc += xb[(size_t)i * P4] * wo;
        }
        acc.x = fmaxf(acc.x, 0.f);
        acc.y = fmaxf(acc.y, 0.f);
        acc.z = fmaxf(acc.z, 0.f);
        acc.w = fmaxf(acc.w, 0.f);

        __builtin_nontemporal_store(acc, out + OUT1_F4 + (size_t)(b * OUTP + o) * P4 + v);
    } else {
        // ---- out1 path: one contiguous 64 KiB slab per block ----
        const int s = blk - 256;            // slab index == (b*32+o)*16+i
        const int b = s >> 9;
        const int o = (s >> 4) & (OUTP - 1);
        const int i = s & (INP - 1);
        const int v = tid;                  // f4 pixel index in [0,256)

        const float wo = w[o * INP + i];    // block-uniform -> scalar load

        // Load the 16 repeat-channels of x for this (b,i) at pixel v.
        const f4* xs = x + (size_t)(b * 256 + i * REPS) * P4 + v;
        f4 xr[16];
#pragma unroll
        for (int r = 0; r < REPS; ++r) xr[r] = xs[(size_t)r * P4];

        // Segment sum S in the exact pairwise order of the original LDS tree
        // (bitwise-identical gate input; absmax must stay 0.0):
        const f4 t0 = (xr[0] + xr[8])  + (xr[4] + xr[12]);
        const f4 t2 = (xr[2] + xr[10]) + (xr[6] + xr[14]);
        const f4 t1 = (xr[1] + xr[9])  + (xr[5] + xr[13]);
        const f4 t3 = (xr[3] + xr[11]) + (xr[7] + xr[15]);
        const f4 S  = (t0 + t2) + (t1 + t3);

        // Stream 16 contiguous 4 KiB rows (64 KiB total, 1 KiB per wave-store).
        f4* dst = out + (size_t)s * (REPS * P4) + v;
#pragma unroll
        for (int r = 0; r < REPS; ++r) {
            const f4 xv = xr[r];
            f4 res;
            res.x = (wo * S.x > 0.f) ? xv.x * wo : 0.f;
            res.y = (wo * S.y > 0.f) ? xv.y * wo : 0.f;
            res.z = (wo * S.z > 0.f) ? xv.z * wo : 0.f;
            res.w = (wo * S.w > 0.f) ? xv.w * wo : 0.f;
            __builtin_nontemporal_store(res, dst + (size_t)r * P4);
        }
    }
}

extern "C" void kernel_launch(void* const* d_in, const int* in_sizes, int n_in,
                              void* d_out, int out_size, void* d_ws, size_t ws_size,
                              hipStream_t stream) {
    const f4* x  = (const f4*)d_in[0];      // (8, 256, 32, 32) fp32
    const f4* x2 = (const f4*)d_in[1];      // (8, 16, 32, 32) fp32
    const float* w = (const float*)d_in[2]; // (512,1,1,1) fp32
    f4* out = (f4*)d_out;

    const int grid = 256 + BB * OUTP * INP;  // out2 blocks + out1 slab blocks

    // Launch TWICE: idempotent; the delta vs round 1's single launch
    // measures the kernel's true duration with fill overhead cancelled.
    qconv_pw_fused<<<grid, 256, 0, stream>>>(x, x2, w, out);
    qconv_pw_fused<<<grid, 256, 0, stream>>>(x, x2, w, out);
}

// Round 3
// 275.836 us; speedup vs baseline: 1.1915x; 1.1915x over previous
//
#include <hip/hip_runtime.h>

// Native 4-wide float vector (lowers to global_load/store_dwordx4).
typedef float f4 __attribute__((ext_vector_type(4)));

// Problem constants (from reference)
constexpr int OUTP = 32;        // OUT_PLANES
constexpr int INP  = 16;        // IN_PLANES
constexpr int REPS = 16;        // REP = 256/16
constexpr int BB   = 8;
constexpr int HW   = 32 * 32;   // 1024 pixels
constexpr int P4   = HW / 4;    // 256 f4 per channel
constexpr size_t OUT1_F4 = (size_t)BB * OUTP * INP * REPS * P4;  // 16777216 f4

// FINAL (single launch). Measured by round-2 double-launch delta:
//   T_kernel = 328.65 - 276.37 = 52.3 us vs ~44.6 us mandatory-traffic floor
//   (269.5 MB writes + ~9 MB HBM reads at the ~6.2 TB/s fill-demonstrated
//   achievable rate) -> ~85% of roofline. Remaining dur_us (~224 us) is
//   harness poison-fill inside the timed graph, not kernel time.
//
//   blocks [0, 256):    relu_out2. One thread per out2 f4 (65536 threads).
//   blocks [256, 4352): out1. One block per contiguous 64 KiB output slab
//                       (b, o, i). Thread t = pixel v: loads the 16
//                       r-channels into registers, forms the segment sum S
//                       in the exact pairwise order of the original LDS
//                       tree (bitwise-identical gate input), then streams
//                       16 contiguous 4 KiB rows with nontemporal stores.
//                       o-sibling blocks (stride 16 == 0 mod 8 XCDs) share
//                       the x slab in the same XCD's L2.
__global__ __launch_bounds__(256, 4) void qconv_pw_fused(
    const f4* __restrict__ x,      // (B, 256, H, W) as f4: (b*256+c)*P4 + v
    const f4* __restrict__ x2,     // (B, 16, H, W)
    const float* __restrict__ w,   // (512,) == w2[o][i] at w[o*16+i]
    f4* __restrict__ out)          // out1 (B,8192,H,W) then relu_out2 (B,32,H,W)
{
    const int blk = blockIdx.x;
    const int tid = threadIdx.x;

    if (blk < 256) {
        // ---- relu_out2 path (first, so it never tails) ----
        const int t    = blk * 256 + tid;          // [0, 65536)
        const int v    = t & (P4 - 1);             // f4 pixel index
        const int rest = t >> 8;                   // [0, 256) = B*OUTP
        const int o    = rest & (OUTP - 1);
        const int b    = rest >> 5;

        const f4* xb = x2 + (size_t)(b * INP) * P4 + v;
        f4 acc = (f4)(0.f);
#pragma unroll
        for (int i = 0; i < INP; ++i) {
            const float wo = w[o * INP + i];       // wave-uniform -> scalar load
            acc += xb[(size_t)i * P4] * wo;
        }
        acc.x = fmaxf(acc.x, 0.f);
        acc.y = fmaxf(acc.y, 0.f);
        acc.z = fmaxf(acc.z, 0.f);
        acc.w = fmaxf(acc.w, 0.f);

        __builtin_nontemporal_store(acc, out + OUT1_F4 + (size_t)(b * OUTP + o) * P4 + v);
    } else {
        // ---- out1 path: one contiguous 64 KiB slab per block ----
        const int s = blk - 256;            // slab index == (b*32+o)*16+i
        const int b = s >> 9;
        const int o = (s >> 4) & (OUTP - 1);
        const int i = s & (INP - 1);
        const int v = tid;                  // f4 pixel index in [0,256)

        const float wo = w[o * INP + i];    // block-uniform -> scalar load

        // Load the 16 repeat-channels of x for this (b,i) at pixel v.
        const f4* xs = x + (size_t)(b * 256 + i * REPS) * P4 + v;
        f4 xr[16];
#pragma unroll
        for (int r = 0; r < REPS; ++r) xr[r] = xs[(size_t)r * P4];

        // Segment sum S in the exact pairwise order of the original LDS tree
        // (bitwise-identical gate input; absmax must stay 0.0):
        const f4 t0 = (xr[0] + xr[8])  + (xr[4] + xr[12]);
        const f4 t2 = (xr[2] + xr[10]) + (xr[6] + xr[14]);
        const f4 t1 = (xr[1] + xr[9])  + (xr[5] + xr[13]);
        const f4 t3 = (xr[3] + xr[11]) + (xr[7] + xr[15]);
        const f4 S  = (t0 + t2) + (t1 + t3);

        // Stream 16 contiguous 4 KiB rows (64 KiB total, 1 KiB per wave-store).
        f4* dst = out + (size_t)s * (REPS * P4) + v;
#pragma unroll
        for (int r = 0; r < REPS; ++r) {
            const f4 xv = xr[r];
            f4 res;
            res.x = (wo * S.x > 0.f) ? xv.x * wo : 0.f;
            res.y = (wo * S.y > 0.f) ? xv.y * wo : 0.f;
            res.z = (wo * S.z > 0.f) ? xv.z * wo : 0.f;
            res.w = (wo * S.w > 0.f) ? xv.w * wo : 0.f;
            __builtin_nontemporal_store(res, dst + (size_t)r * P4);
        }
    }
}

extern "C" void kernel_launch(void* const* d_in, const int* in_sizes, int n_in,
                              void* d_out, int out_size, void* d_ws, size_t ws_size,
                              hipStream_t stream) {
    const f4* x  = (const f4*)d_in[0];      // (8, 256, 32, 32) fp32
    const f4* x2 = (const f4*)d_in[1];      // (8, 16, 32, 32) fp32
    const float* w = (const float*)d_in[2]; // (512,1,1,1) fp32
    f4* out = (f4*)d_out;

    const int grid = 256 + BB * OUTP * INP;  // out2 blocks + out1 slab blocks
    qconv_pw_fused<<<grid, 256, 0, stream>>>(x, x2, w, out);
}